// Round 15
// baseline (321.069 us; speedup 1.0000x reference)
//
#include <hip/hip_runtime.h>
#include <hip/hip_bf16.h>

// NA Spatial MSA, fused:  out = attn @ (xw @ (Vv@Wo)) + bo
// R15 = R14 pipeline at HALF-WINDOW granularity so LDS fits 2 blocks/CU:
//   LDS 80KB = 2x 32KB x-half buffers (f32, DMA, pre-swizzled src)
//            + 2x 8KB attn bf16. 2 blocks x 512thr = 16 waves/CU: the
//   second block's waves fill every DMA-drain stall of the first (R14 ran
//   1 block/CU, 21% occupancy, ALL pipes <40% busy -> latency-bound).
// Keeps: WT hoist (R13, zero tracked loads in compute), DMA staging (R7),
// AWR before stores (counted-cheap wait), vmcnt(32) window-end (stores ride).
// Phase cadence: [stage half^1 | compute half] -> vmcnt(0) barrier -> flip.

typedef __bf16 bf16x8 __attribute__((ext_vector_type(8)));
typedef __bf16 bf16x4 __attribute__((ext_vector_type(4)));
typedef float  f32x16 __attribute__((ext_vector_type(16)));
typedef float  f32x4  __attribute__((ext_vector_type(4)));
typedef unsigned int uint;
typedef uint   uint4v __attribute__((ext_vector_type(4)));

#define MFMA32(a, b, c) __builtin_amdgcn_mfma_f32_32x32x16_bf16(a, b, c, 0, 0, 0)

// ---------------- Stage 0: WT = (Wv @ Wo)^T in bf16 ----------------
__global__ void wfuse_kernel(const float* __restrict__ Wv,
                             const float* __restrict__ Wo,
                             __bf16* __restrict__ WT) {
  const int n = blockIdx.x;
  const int k = threadIdx.x;
  const float* wvrow = Wv + k * 256;
  float acc = 0.f;
#pragma unroll 4
  for (int j = 0; j < 256; j += 4) {
    f32x4 wv = *(const f32x4*)(wvrow + j);
    acc += wv.x * Wo[(j + 0) * 256 + n];
    acc += wv.y * Wo[(j + 1) * 256 + n];
    acc += wv.z * Wo[(j + 2) * 256 + n];
    acc += wv.w * Wo[(j + 3) * 256 + n];
  }
  WT[n * 256 + k] = (__bf16)acc;
}

static __device__ __forceinline__ uint pkbf(float lo, float hi) {
  return (uint)__builtin_bit_cast(unsigned short, (__bf16)lo) |
         ((uint)__builtin_bit_cast(unsigned short, (__bf16)hi) << 16);
}

// GEMM2 B-frags from GEMM1 acc via pack + shfl_xor(32). (verified R3/R5/R7)
static __device__ __forceinline__ void build_bfrags(const f32x16 acc, int lh,
                                                    bf16x8* bf) {
  uint wd0 = pkbf(acc[0],  acc[1]);
  uint wd1 = pkbf(acc[2],  acc[3]);
  uint wd2 = pkbf(acc[4],  acc[5]);
  uint wd3 = pkbf(acc[6],  acc[7]);
  uint wd4 = pkbf(acc[8],  acc[9]);
  uint wd5 = pkbf(acc[10], acc[11]);
  uint wd6 = pkbf(acc[12], acc[13]);
  uint wd7 = pkbf(acc[14], acc[15]);
  {
    uint o0 = (uint)__shfl_xor((int)wd2, 32);
    uint o1 = (uint)__shfl_xor((int)wd3, 32);
    uint o2 = (uint)__shfl_xor((int)wd0, 32);
    uint o3 = (uint)__shfl_xor((int)wd1, 32);
    uint4v uv = { lh ? o0 : wd0, lh ? o1 : wd1,
                  lh ? wd2 : o2, lh ? wd3 : o3 };
    bf[0] = __builtin_bit_cast(bf16x8, uv);
  }
  {
    uint o0 = (uint)__shfl_xor((int)wd6, 32);
    uint o1 = (uint)__shfl_xor((int)wd7, 32);
    uint o2 = (uint)__shfl_xor((int)wd4, 32);
    uint o3 = (uint)__shfl_xor((int)wd5, 32);
    uint4v uv = { lh ? o0 : wd4, lh ? o1 : wd5,
                  lh ? wd6 : o2, lh ? wd7 : o3 };
    bf[1] = __builtin_bit_cast(bf16x8, uv);
  }
}

static __device__ __forceinline__ long wbase(int w) {
  int wi = w & 31;
  int hi = (w >> 5) & 31;
  int b  = w >> 10;
  return (((long)(b * 256 + hi * 8)) * 256 + wi * 8) * 256;
}

// async 16B/lane global->LDS DMA (LDS dest = wave-uniform base + lane*16)
static __device__ __forceinline__ void dma16(const float* gp, char* lp) {
  __builtin_amdgcn_global_load_lds(
      (const __attribute__((address_space(1))) uint*)gp,
      (__attribute__((address_space(3))) uint*)lp, 16, 0, 0);
}

// read bf16x8 A-frag from half-K f32 x strip: tok row = 512B, granule g
// (16B, 0..31) lives at slot g ^ (tok&31).  (R10-verified layout)
static __device__ __forceinline__ bf16x8 ldax_h(const char* xs, int tok, int g) {
  const int sw = tok & 31;
  f32x4 u = *(const f32x4*)(xs + tok * 512 + ((g ^ sw) << 4));
  f32x4 v = *(const f32x4*)(xs + tok * 512 + (((g + 1) ^ sw) << 4));
  bf16x8 r;
  r[0] = (__bf16)u.x; r[1] = (__bf16)u.y; r[2] = (__bf16)u.z; r[3] = (__bf16)u.w;
  r[4] = (__bf16)v.x; r[5] = (__bf16)v.y; r[6] = (__bf16)v.z; r[7] = (__bf16)v.w;
  return r;
}

// ---------------- Main kernel ----------------
// LDS 80KB: x half-bufs at 0 / 32768 (32KB f32 each); attn bf16 at
// 65536 + sel*8192. 2 blocks/CU (2x81920 = 160KiB exactly).
__global__ __launch_bounds__(512, 4)
void na_msa_kernel(const float* __restrict__ x,
                   const float* __restrict__ attn,
                   const __bf16* __restrict__ WT,
                   const float* __restrict__ bo,
                   float* __restrict__ out) {
  __shared__ char lds[81920];

  const int t    = threadIdx.x;
  const int lane = t & 63;
  const int wvi  = t >> 6;              // wave 0..7, owns ch [32wvi, 32wvi+32)
  const int ln31 = lane & 31;
  const int lh   = lane >> 5;

  const __bf16* wtp = WT + (wvi * 32 + ln31) * 256 + 8 * lh;
  const float bv = bo[wvi * 32 + ln31];

  // attn staging geometry: thread t handles f32x4 idx {t, 512+t}
  const int arow0 = t >> 4;             // row for chunk 0 (chunk 1: +32)
  const int ak0   = (t & 15) * 4;

  const int w0 = blockIdx.x * 8;

  // stage one 32KB K-half of window W into buffer at BUFOFF.
  // 32 DMAs (4/wave); DMA tp covers tok pair {2tp, 2tp+1} (lane>>5 selects);
  // source granule perm = (lane&31)^(tok&31) pre-swizzles for ldax_h.
#define STAGE_XH(W, HALF, BUFOFF) do {                                     \
    const float* xp_ = x + wbase(W);                                       \
    _Pragma("unroll")                                                      \
    for (int jj = 0; jj < 4; ++jj) {                                       \
      int tp_ = jj * 8 + wvi;                                              \
      int tok_ = tp_ * 2 + (lane >> 5);                                    \
      int perm_ = (lane & 31) ^ (tok_ & 31);                               \
      const float* gp_ = xp_ + (tok_ >> 3) * 65536 + (tok_ & 7) * 256 +    \
                         (HALF) * 128 + perm_ * 4;                         \
      int off_ = __builtin_amdgcn_readfirstlane((BUFOFF) + tp_ * 1024);    \
      dma16(gp_, lds + off_);                                              \
    } } while (0)

#define AWR(BAT, R0, R1) do {                                              \
    *(bf16x4*)((BAT) + arow0 * 128 + ((ak0 * 2) ^ ((arow0 & 7) << 4))) =   \
        bf16x4{ (__bf16)(R0).x, (__bf16)(R0).y, (__bf16)(R0).z, (__bf16)(R0).w }; \
    int row1_ = 32 + arow0;                                                \
    *(bf16x4*)((BAT) + row1_ * 128 + ((ak0 * 2) ^ ((row1_ & 7) << 4))) =   \
        bf16x4{ (__bf16)(R1).x, (__bf16)(R1).y, (__bf16)(R1).z, (__bf16)(R1).w }; \
    } while (0)

  // ---- prologue: hoist the 16 loop-invariant WT b0 frags into VGPRs ----
  bf16x8 wb[16];
#pragma unroll
  for (int ks = 0; ks < 16; ++ks) wb[ks] = *(const bf16x8*)(wtp + ks * 16);

  // ---- prologue: stage (w0, half 0) + attn(w0) ----
  {
    const float* ap = attn + (long)w0 * 4096;
    f32x4 a0 = *(const f32x4*)(ap + t * 4);
    f32x4 a1 = *(const f32x4*)(ap + (512 + t) * 4);
    STAGE_XH(w0, 0, 0);
    AWR(lds + 65536, a0, a1);
  }
  asm volatile("s_waitcnt vmcnt(0) lgkmcnt(0)" ::: "memory");
  __builtin_amdgcn_s_barrier();
  __builtin_amdgcn_sched_barrier(0);

#pragma unroll 1
  for (int i = 0; i < 8; ++i) {
    const int w = w0 + i;
    const char* as = lds + 65536 + (i & 1) * 8192;

    // ======== PHASE 0: stage (w, half1)->bufB; compute half0 from bufA ====
    f32x4 ra0, ra1;
    if (i < 7) {                         // next window's attn loads (oldest)
      const float* ap = attn + (long)(w + 1) * 4096;
      ra0 = *(const f32x4*)(ap + t * 4);
      ra1 = *(const f32x4*)(ap + (512 + t) * 4);
    }
    STAGE_XH(w, 1, 32768);
    __builtin_amdgcn_sched_barrier(0);

    f32x16 acc0 = {}, acc1 = {};
#pragma unroll
    for (int ks = 0; ks < 8; ++ks) {
      int g = 4 * ks + 2 * lh;
      bf16x8 a0 = ldax_h(lds, ln31, g);            // toks 0..31
      bf16x8 a1 = ldax_h(lds, 32 + ln31, g);       // toks 32..63
      acc0 = MFMA32(a0, wb[ks], acc0);
      acc1 = MFMA32(a1, wb[ks], acc1);
    }
    asm volatile("s_waitcnt vmcnt(0) lgkmcnt(0)" ::: "memory");
    __builtin_amdgcn_s_barrier();
    __builtin_amdgcn_sched_barrier(0);

    // ======== PHASE 1: stage (w+1, half0)->bufA; compute half1 from bufB ==
    if (i < 7) STAGE_XH(w + 1, 0, 0);
    __builtin_amdgcn_sched_barrier(0);

#pragma unroll
    for (int ks = 8; ks < 16; ++ks) {
      int g = 4 * (ks - 8) + 2 * lh;
      bf16x8 a0 = ldax_h(lds + 32768, ln31, g);
      bf16x8 a1 = ldax_h(lds + 32768, 32 + ln31, g);
      acc0 = MFMA32(a0, wb[ks], acc0);
      acc1 = MFMA32(a1, wb[ks], acc1);
    }

    // ---- GEMM2 B-frags in-register ----
    bf16x8 bfr[4];
    build_bfrags(acc0, lh, &bfr[0]);
    build_bfrags(acc1, lh, &bfr[2]);

    // ---- GEMM2: out = attn @ z, K=64 (attn bf16 LDS) ----
    f32x16 o0 = {}, o1 = {};
#pragma unroll
    for (int ks = 0; ks < 4; ++ks) {
      int kk = ks * 16 + 8 * lh;
      int ab0 = ln31 * 128 + ((kk * 2) ^ ((ln31 & 7) << 4));
      bf16x8 a0 = *(const bf16x8*)(as + ab0);
      bf16x8 a1 = *(const bf16x8*)(as + ab0 + 4096);
      o0 = MFMA32(a0, bfr[ks], o0);
      o1 = MFMA32(a1, bfr[ks], o1);
    }

    // ---- attn cvt+ds_write for w+1 BEFORE stores: its compiler wait is
    // vmcnt(32) (newer = this phase's 32 riding DMAs) -> counted-cheap. ----
    if (i < 7) {
      AWR(lds + 65536 + ((i + 1) & 1) * 8192, ra0, ra1);
    }
    __builtin_amdgcn_sched_barrier(0);

    // ---- epilogue: + bo, scatter-store window w (32 dword stores) ----
    {
      float* op = out + wbase(w);
      const int ch = wvi * 32 + ln31;
#pragma unroll
      for (int r = 0; r < 16; ++r) {
        int tok = (r & 3) + 8 * (r >> 2) + 4 * lh;
        op[(tok >> 3) * 65536 + (tok & 7) * 256 + ch] = o0[r] + bv;
      }
#pragma unroll
      for (int r = 0; r < 16; ++r) {
        int tok = 32 + (r & 3) + 8 * (r >> 2) + 4 * lh;
        op[(tok >> 3) * 65536 + (tok & 7) * 256 + ch] = o1[r] + bv;
      }
    }

    // ---- window-end: stores (newest 32) ride; DMAs (older) forced. ----
    asm volatile("s_waitcnt vmcnt(32) lgkmcnt(0)" ::: "memory");
    __builtin_amdgcn_s_barrier();
    __builtin_amdgcn_sched_barrier(0);
  }
#undef STAGE_XH
#undef AWR
}

extern "C" void kernel_launch(void* const* d_in, const int* in_sizes, int n_in,
                              void* d_out, int out_size, void* d_ws, size_t ws_size,
                              hipStream_t stream) {
  const float* x    = (const float*)d_in[0];
  const float* attn = (const float*)d_in[1];
  const float* Wv   = (const float*)d_in[2];
  const float* Wo   = (const float*)d_in[3];
  const float* bo   = (const float*)d_in[4];
  float* out = (float*)d_out;
  __bf16* WT = (__bf16*)d_ws;   // 256*256*2 = 128 KB scratch

  wfuse_kernel<<<256, 256, 0, stream>>>(Wv, Wo, WT);
  na_msa_kernel<<<512, 512, 0, stream>>>(x, attn, WT, bo, out);
}

// Round 16
// 150.491 us; speedup vs baseline: 2.1335x; 2.1335x over previous
//
#include <hip/hip_runtime.h>
#include <hip/hip_bf16.h>

// NA Spatial MSA, fused:  out = attn @ (xw @ (Wv@Wo)) + bo
// R16 = R15 (80KB half-window pipeline, 2 blocks/CU) with the spill fixed:
//  - __launch_bounds__(512, 2): the ONLY config the allocator handles sanely
//    (R13/R14: 96-104 VGPR, no spill; every other hint -> 64-cap + spill).
//  - GEMM2 computes and STORES o0 before computing o1 (peak pressure
//    wb64+bfr16+o16 ~= 110 instead of ~135).
// Keeps all proven pieces: DMA staging, WT hoist (zero tracked loads in
// compute), attn loads issued oldest, counted vmcnt drains.

typedef __bf16 bf16x8 __attribute__((ext_vector_type(8)));
typedef __bf16 bf16x4 __attribute__((ext_vector_type(4)));
typedef float  f32x16 __attribute__((ext_vector_type(16)));
typedef float  f32x4  __attribute__((ext_vector_type(4)));
typedef unsigned int uint;
typedef uint   uint4v __attribute__((ext_vector_type(4)));

#define MFMA32(a, b, c) __builtin_amdgcn_mfma_f32_32x32x16_bf16(a, b, c, 0, 0, 0)

// ---------------- Stage 0: WT = (Wv @ Wo)^T in bf16 ----------------
__global__ void wfuse_kernel(const float* __restrict__ Wv,
                             const float* __restrict__ Wo,
                             __bf16* __restrict__ WT) {
  const int n = blockIdx.x;
  const int k = threadIdx.x;
  const float* wvrow = Wv + k * 256;
  float acc = 0.f;
#pragma unroll 4
  for (int j = 0; j < 256; j += 4) {
    f32x4 wv = *(const f32x4*)(wvrow + j);
    acc += wv.x * Wo[(j + 0) * 256 + n];
    acc += wv.y * Wo[(j + 1) * 256 + n];
    acc += wv.z * Wo[(j + 2) * 256 + n];
    acc += wv.w * Wo[(j + 3) * 256 + n];
  }
  WT[n * 256 + k] = (__bf16)acc;
}

static __device__ __forceinline__ uint pkbf(float lo, float hi) {
  return (uint)__builtin_bit_cast(unsigned short, (__bf16)lo) |
         ((uint)__builtin_bit_cast(unsigned short, (__bf16)hi) << 16);
}

// GEMM2 B-frags from GEMM1 acc via pack + shfl_xor(32). (verified R3/R5/R7)
static __device__ __forceinline__ void build_bfrags(const f32x16 acc, int lh,
                                                    bf16x8* bf) {
  uint wd0 = pkbf(acc[0],  acc[1]);
  uint wd1 = pkbf(acc[2],  acc[3]);
  uint wd2 = pkbf(acc[4],  acc[5]);
  uint wd3 = pkbf(acc[6],  acc[7]);
  uint wd4 = pkbf(acc[8],  acc[9]);
  uint wd5 = pkbf(acc[10], acc[11]);
  uint wd6 = pkbf(acc[12], acc[13]);
  uint wd7 = pkbf(acc[14], acc[15]);
  {
    uint o0 = (uint)__shfl_xor((int)wd2, 32);
    uint o1 = (uint)__shfl_xor((int)wd3, 32);
    uint o2 = (uint)__shfl_xor((int)wd0, 32);
    uint o3 = (uint)__shfl_xor((int)wd1, 32);
    uint4v uv = { lh ? o0 : wd0, lh ? o1 : wd1,
                  lh ? wd2 : o2, lh ? wd3 : o3 };
    bf[0] = __builtin_bit_cast(bf16x8, uv);
  }
  {
    uint o0 = (uint)__shfl_xor((int)wd6, 32);
    uint o1 = (uint)__shfl_xor((int)wd7, 32);
    uint o2 = (uint)__shfl_xor((int)wd4, 32);
    uint o3 = (uint)__shfl_xor((int)wd5, 32);
    uint4v uv = { lh ? o0 : wd4, lh ? o1 : wd5,
                  lh ? wd6 : o2, lh ? wd7 : o3 };
    bf[1] = __builtin_bit_cast(bf16x8, uv);
  }
}

static __device__ __forceinline__ long wbase(int w) {
  int wi = w & 31;
  int hi = (w >> 5) & 31;
  int b  = w >> 10;
  return (((long)(b * 256 + hi * 8)) * 256 + wi * 8) * 256;
}

// async 16B/lane global->LDS DMA (LDS dest = wave-uniform base + lane*16)
static __device__ __forceinline__ void dma16(const float* gp, char* lp) {
  __builtin_amdgcn_global_load_lds(
      (const __attribute__((address_space(1))) uint*)gp,
      (__attribute__((address_space(3))) uint*)lp, 16, 0, 0);
}

// read bf16x8 A-frag from half-K f32 x strip: tok row = 512B, granule g
// (16B, 0..31) lives at slot g ^ (tok&31).  (R10-verified layout)
static __device__ __forceinline__ bf16x8 ldax_h(const char* xs, int tok, int g) {
  const int sw = tok & 31;
  f32x4 u = *(const f32x4*)(xs + tok * 512 + ((g ^ sw) << 4));
  f32x4 v = *(const f32x4*)(xs + tok * 512 + (((g + 1) ^ sw) << 4));
  bf16x8 r;
  r[0] = (__bf16)u.x; r[1] = (__bf16)u.y; r[2] = (__bf16)u.z; r[3] = (__bf16)u.w;
  r[4] = (__bf16)v.x; r[5] = (__bf16)v.y; r[6] = (__bf16)v.z; r[7] = (__bf16)v.w;
  return r;
}

// ---------------- Main kernel ----------------
// LDS 80KB: x half-bufs at 0 / 32768 (32KB f32 each); attn bf16 at
// 65536 + sel*8192. 2 blocks/CU (2x81920 <= 160KiB).
__global__ __launch_bounds__(512, 2)
void na_msa_kernel(const float* __restrict__ x,
                   const float* __restrict__ attn,
                   const __bf16* __restrict__ WT,
                   const float* __restrict__ bo,
                   float* __restrict__ out) {
  __shared__ char lds[81920];

  const int t    = threadIdx.x;
  const int lane = t & 63;
  const int wvi  = t >> 6;              // wave 0..7, owns ch [32wvi, 32wvi+32)
  const int ln31 = lane & 31;
  const int lh   = lane >> 5;

  const __bf16* wtp = WT + (wvi * 32 + ln31) * 256 + 8 * lh;
  const float bv = bo[wvi * 32 + ln31];

  // attn staging geometry: thread t handles f32x4 idx {t, 512+t}
  const int arow0 = t >> 4;             // row for chunk 0 (chunk 1: +32)
  const int ak0   = (t & 15) * 4;

  const int w0 = blockIdx.x * 8;

  // stage one 32KB K-half of window W into buffer at BUFOFF.
  // 32 DMAs (4/wave); DMA tp covers tok pair {2tp, 2tp+1} (lane>>5 selects);
  // source granule perm = (lane&31)^(tok&31) pre-swizzles for ldax_h.
#define STAGE_XH(W, HALF, BUFOFF) do {                                     \
    const float* xp_ = x + wbase(W);                                       \
    _Pragma("unroll")                                                      \
    for (int jj = 0; jj < 4; ++jj) {                                       \
      int tp_ = jj * 8 + wvi;                                              \
      int tok_ = tp_ * 2 + (lane >> 5);                                    \
      int perm_ = (lane & 31) ^ (tok_ & 31);                               \
      const float* gp_ = xp_ + (tok_ >> 3) * 65536 + (tok_ & 7) * 256 +    \
                         (HALF) * 128 + perm_ * 4;                         \
      int off_ = __builtin_amdgcn_readfirstlane((BUFOFF) + tp_ * 1024);    \
      dma16(gp_, lds + off_);                                              \
    } } while (0)

#define AWR(BAT, R0, R1) do {                                              \
    *(bf16x4*)((BAT) + arow0 * 128 + ((ak0 * 2) ^ ((arow0 & 7) << 4))) =   \
        bf16x4{ (__bf16)(R0).x, (__bf16)(R0).y, (__bf16)(R0).z, (__bf16)(R0).w }; \
    int row1_ = 32 + arow0;                                                \
    *(bf16x4*)((BAT) + row1_ * 128 + ((ak0 * 2) ^ ((row1_ & 7) << 4))) =   \
        bf16x4{ (__bf16)(R1).x, (__bf16)(R1).y, (__bf16)(R1).z, (__bf16)(R1).w }; \
    } while (0)

  // ---- prologue: hoist the 16 loop-invariant WT b0 frags into VGPRs ----
  bf16x8 wb[16];
#pragma unroll
  for (int ks = 0; ks < 16; ++ks) wb[ks] = *(const bf16x8*)(wtp + ks * 16);

  // ---- prologue: stage (w0, half 0) + attn(w0) ----
  {
    const float* ap = attn + (long)w0 * 4096;
    f32x4 a0 = *(const f32x4*)(ap + t * 4);
    f32x4 a1 = *(const f32x4*)(ap + (512 + t) * 4);
    STAGE_XH(w0, 0, 0);
    AWR(lds + 65536, a0, a1);
  }
  asm volatile("s_waitcnt vmcnt(0) lgkmcnt(0)" ::: "memory");
  __builtin_amdgcn_s_barrier();
  __builtin_amdgcn_sched_barrier(0);

#pragma unroll 1
  for (int i = 0; i < 8; ++i) {
    const int w = w0 + i;
    const char* as = lds + 65536 + (i & 1) * 8192;

    // ======== PHASE 0: stage (w, half1)->bufB; compute half0 from bufA ====
    f32x4 ra0, ra1;
    if (i < 7) {                         // next window's attn loads (oldest)
      const float* ap = attn + (long)(w + 1) * 4096;
      ra0 = *(const f32x4*)(ap + t * 4);
      ra1 = *(const f32x4*)(ap + (512 + t) * 4);
    }
    STAGE_XH(w, 1, 32768);
    __builtin_amdgcn_sched_barrier(0);

    f32x16 acc0 = {}, acc1 = {};
#pragma unroll
    for (int ks = 0; ks < 8; ++ks) {
      int g = 4 * ks + 2 * lh;
      bf16x8 a0 = ldax_h(lds, ln31, g);            // toks 0..31
      bf16x8 a1 = ldax_h(lds, 32 + ln31, g);       // toks 32..63
      acc0 = MFMA32(a0, wb[ks], acc0);
      acc1 = MFMA32(a1, wb[ks], acc1);
    }
    asm volatile("s_waitcnt vmcnt(0) lgkmcnt(0)" ::: "memory");
    __builtin_amdgcn_s_barrier();
    __builtin_amdgcn_sched_barrier(0);

    // ======== PHASE 1: stage (w+1, half0)->bufA; compute half1 from bufB ==
    if (i < 7) STAGE_XH(w + 1, 0, 0);
    __builtin_amdgcn_sched_barrier(0);

#pragma unroll
    for (int ks = 8; ks < 16; ++ks) {
      int g = 4 * (ks - 8) + 2 * lh;
      bf16x8 a0 = ldax_h(lds + 32768, ln31, g);
      bf16x8 a1 = ldax_h(lds + 32768, 32 + ln31, g);
      acc0 = MFMA32(a0, wb[ks], acc0);
      acc1 = MFMA32(a1, wb[ks], acc1);
    }

    // ---- GEMM2 B-frags in-register (accs die here) ----
    bf16x8 bfr[4];
    build_bfrags(acc0, lh, &bfr[0]);
    build_bfrags(acc1, lh, &bfr[2]);

    // ---- attn cvt+ds_write for w+1: counted-cheap wait (attn oldest;
    // the 32 phase-1 DMAs are newer and keep riding). ----
    if (i < 7) {
      AWR(lds + 65536 + ((i + 1) & 1) * 8192, ra0, ra1);
    }

    float* op = out + wbase(w);
    const int ch = wvi * 32 + ln31;

    // ---- GEMM2 + store, SPLIT to cap register pressure:
    //      o0 (out-toks 0..31) -> store -> o1 (out-toks 32..63) -> store ----
    {
      f32x16 o0 = {};
#pragma unroll
      for (int ks = 0; ks < 4; ++ks) {
        int kk = ks * 16 + 8 * lh;
        int ab0 = ln31 * 128 + ((kk * 2) ^ ((ln31 & 7) << 4));
        bf16x8 a0 = *(const bf16x8*)(as + ab0);
        o0 = MFMA32(a0, bfr[ks], o0);
      }
#pragma unroll
      for (int r = 0; r < 16; ++r) {
        int tok = (r & 3) + 8 * (r >> 2) + 4 * lh;
        op[(tok >> 3) * 65536 + (tok & 7) * 256 + ch] = o0[r] + bv;
      }
    }
    {
      f32x16 o1 = {};
#pragma unroll
      for (int ks = 0; ks < 4; ++ks) {
        int kk = ks * 16 + 8 * lh;
        int ab0 = ln31 * 128 + ((kk * 2) ^ ((ln31 & 7) << 4));
        bf16x8 a1 = *(const bf16x8*)(as + ab0 + 4096);
        o1 = MFMA32(a1, bfr[ks], o1);
      }
#pragma unroll
      for (int r = 0; r < 16; ++r) {
        int tok = 32 + (r & 3) + 8 * (r >> 2) + 4 * lh;
        op[(tok >> 3) * 65536 + (tok & 7) * 256 + ch] = o1[r] + bv;
      }
    }

    // ---- window-end: stores (newest 32) ride; DMAs (older) forced. ----
    asm volatile("s_waitcnt vmcnt(32) lgkmcnt(0)" ::: "memory");
    __builtin_amdgcn_s_barrier();
    __builtin_amdgcn_sched_barrier(0);
  }
#undef STAGE_XH
#undef AWR
}

extern "C" void kernel_launch(void* const* d_in, const int* in_sizes, int n_in,
                              void* d_out, int out_size, void* d_ws, size_t ws_size,
                              hipStream_t stream) {
  const float* x    = (const float*)d_in[0];
  const float* attn = (const float*)d_in[1];
  const float* Wv   = (const float*)d_in[2];
  const float* Wo   = (const float*)d_in[3];
  const float* bo   = (const float*)d_in[4];
  float* out = (float*)d_out;
  __bf16* WT = (__bf16*)d_ws;   // 256*256*2 = 128 KB scratch

  wfuse_kernel<<<256, 256, 0, stream>>>(Wv, Wo, WT);
  na_msa_kernel<<<512, 512, 0, stream>>>(x, attn, WT, bo, out);
}